// Round 9
// baseline (77.333 us; speedup 1.0000x reference)
//
#include <hip/hip_runtime.h>

namespace {

constexpr int F     = 128;
constexpr int L     = 4096;
constexpr int NTASK = 4096;   // 131072 rows / 32 rows per task
constexpr int NB    = 1024;   // blocks

using short8 = __attribute__((ext_vector_type(8))) short;
using f32x16 = __attribute__((ext_vector_type(16))) float;
using u32x4  = __attribute__((ext_vector_type(4))) unsigned int;

__device__ inline unsigned short f2bf(float x) {
    unsigned u = __builtin_bit_cast(unsigned, x);
    unsigned r = (u + 0x7fffu + ((u >> 16) & 1u)) >> 16;
    return (unsigned short)r;
}

__device__ inline unsigned pack2(float lo, float hi) {
    return (unsigned)f2bf(lo) | ((unsigned)f2bf(hi) << 16);
}

__device__ inline short8 cvt8(float4 a, float4 b) {
    u32x4 u;
    u[0] = pack2(a.x, a.y);
    u[1] = pack2(a.z, a.w);
    u[2] = pack2(b.x, b.y);
    u[3] = pack2(b.z, b.w);
    return __builtin_bit_cast(short8, u);
}

// Head-folded weights packed as 32x32x16 MFMA A-fragments:
//   chunk c = cg*16 + s (cg: col-group 0..3, s: k-step 0..15), lane l, j 0..7
//   Wf[(c*64 + l)*8 + j] = Wbar[k][n],  k = s*16 + (l>>5)*8 + j,
//                                       n = cg*32 + (l&31)
//   Wbar[k][n]: k<128 -> mean_h W_src[(h*128+n)*128+k]
//              k>=128 -> mean_h W_res[(h*128+n)*128+(k-128)]
__global__ void prep(const float* __restrict__ Wsrc,
                     const float* __restrict__ Wres,
                     const float* __restrict__ bias,
                     unsigned short* __restrict__ Wf,
                     float* __restrict__ bbar)
{
    int idx = blockIdx.x * 256 + threadIdx.x;
    if (idx < 2 * F * F) {
        int j  = idx & 7;
        int r  = idx >> 3;
        int l  = r & 63;
        int c  = r >> 6;          // 0..63
        int cg = c >> 4;
        int s  = c & 15;
        int k  = s * 16 + ((l >> 5) << 3) + j;
        int n  = (cg << 5) + (l & 31);
        int e  = k & (F - 1);
        const float* W = (k < F) ? Wsrc : Wres;
        float sum = 0.f;
#pragma unroll
        for (int h = 0; h < 8; ++h) sum += W[(h * F + n) * F + e];
        Wf[idx] = f2bf(sum * 0.125f);
    }
    if (idx < F) {
        float s = 0.f;
#pragma unroll
        for (int h = 0; h < 8; ++h) s += bias[h * F + idx];
        bbar[idx] = s * 0.125f;
    }
}

// No LDS, no barriers. Wave = 32 output rows x 32 cols per task; W slice
// lives in 64 VGPRs for the whole kernel; lane = one output row.
__global__ __launch_bounds__(256, 4)
void gat32(const float* __restrict__ loc,
           const unsigned short* __restrict__ Wf,
           const float* __restrict__ bbar,
           float* __restrict__ out)
{
    const int t    = threadIdx.x;
    const int lane = t & 63;
    const int cg   = t >> 6;       // col-group 0..3
    const int l31  = lane & 31;
    const int h    = lane >> 5;

    // persistent W fragments (16 x short8 = 64 VGPR)
    short8 wf[16];
#pragma unroll
    for (int s = 0; s < 16; ++s)
        wf[s] = *(const short8*)(Wf + (((cg * 16 + s) * 64 + lane) << 3));

    const int cbase = cg * 32 + h * 4;
    float4 bb[4];
#pragma unroll
    for (int q = 0; q < 4; ++q) bb[q] = *(const float4*)(bbar + cbase + q * 8);

    for (int task = blockIdx.x; task < NTASK; task += NB) {
        const int row  = task * 32 + l31;
        const int prow = ((row & (L - 1)) == 0) ? row : row - 1;  // value unused at p==0 (fixup)
        const float* cp = loc + (size_t)row  * F + h * 8;
        const float* pp = loc + (size_t)prow * F + h * 8;

        f32x16 acc;
#pragma unroll
        for (int i = 0; i < 16; ++i) acc[i] = 0.f;

        // k-steps: s<8 reads prev row (k=0..127), s>=8 reads cur row (k=128..255)
        float4 a0 = *(const float4*)(pp);
        float4 a1 = *(const float4*)(pp + 4);
        float4 b0, b1;
#pragma unroll
        for (int s = 0; s < 16; s += 2) {
            {   // prefetch s+1
                const float* q = (s + 1 < 8) ? (pp + (s + 1) * 16) : (cp + (s - 7) * 16);
                b0 = *(const float4*)(q);
                b1 = *(const float4*)(q + 4);
            }
            acc = __builtin_amdgcn_mfma_f32_32x32x16_bf16(wf[s], cvt8(a0, a1), acc, 0, 0, 0);
            if (s + 2 < 16) {   // prefetch s+2
                const float* q = (s + 2 < 8) ? (pp + (s + 2) * 16) : (cp + (s - 6) * 16);
                a0 = *(const float4*)(q);
                a1 = *(const float4*)(q + 4);
            }
            acc = __builtin_amdgcn_mfma_f32_32x32x16_bf16(wf[s + 1], cvt8(b0, b1), acc, 0, 0, 0);
        }

        // epilogue: lane owns row `row`; D: col(lane&31)=row-slot,
        // reg r -> out-col cg*32 + (r&3) + 8*(r>>2) + 4*h
        float* orow = out + (size_t)row * F;
        const bool isfirst = ((row & (L - 1)) == 0);
#pragma unroll
        for (int q = 0; q < 4; ++q) {
            int c0 = cbase + q * 8;
            float4 v = make_float4(acc[q * 4 + 0] + bb[q].x, acc[q * 4 + 1] + bb[q].y,
                                   acc[q * 4 + 2] + bb[q].z, acc[q * 4 + 3] + bb[q].w);
            if (isfirst) v = *(const float4*)(loc + (size_t)row * F + c0);  // out[b,0,:]=loc[b,0,:]
            *(float4*)(orow + c0) = v;
        }
    }
}

} // namespace

extern "C" void kernel_launch(void* const* d_in, const int* in_sizes, int n_in,
                              void* d_out, int out_size, void* d_ws, size_t ws_size,
                              hipStream_t stream) {
    const float* loc  = (const float*)d_in[0];
    const float* Wsrc = (const float*)d_in[1];
    // d_in[2] W_dst, d_in[3] attn_l, d_in[4] attn_r cancel (alpha == 1)
    const float* Wres = (const float*)d_in[5];
    const float* bias = (const float*)d_in[6];

    unsigned short* Wf   = (unsigned short*)d_ws;          // 32768 bf16 = 64 KB
    float*          bbar = (float*)((char*)d_ws + 2 * F * F * 2);
    float*          outp = (float*)d_out;

    prep<<<128, 256, 0, stream>>>(Wsrc, Wres, bias, Wf, bbar);

    gat32<<<NB, 256, 0, stream>>>(loc, Wf, bbar, outp);
}